// Round 1
// baseline (475.369 us; speedup 1.0000x reference)
//
#include <hip/hip_runtime.h>
#include <hip/hip_bf16.h>

// ---------------------------------------------------------------------------
// PetaloMixer: LN -> (x4 groups) mamba block -> residual -> LN -> proj
// B=2, C=256, L=4096 (16^3), d_model=64, d_inner=128, d_state=16, d_conv=4,
// dt_rank=4. Mamba batches N=8 (4 groups x B), rows = N*L = 32768.
// All inputs/outputs fp32.
// ---------------------------------------------------------------------------

#define LOG2E 1.4426950408889634f

__device__ __forceinline__ float softplusf(float x) {
    return (x > 20.f) ? x : log1pf(__expf(x));
}

// ---------------- LayerNorm 1: x[(n,c),l] -> parts[np=(p*2+n)][l][c'] -------
__global__ __launch_bounds__(256) void ln1_kernel(
    const float* __restrict__ x, const float* __restrict__ g,
    const float* __restrict__ b, float* __restrict__ parts) {
    int bid = blockIdx.x;          // 8192 = 2n * 4096l
    int n = bid >> 12, l = bid & 4095;
    int c = threadIdx.x;           // 256
    float v = x[((size_t)(n * 256 + c)) * 4096 + l];
    float s = v, sq = v * v;
    #pragma unroll
    for (int off = 32; off > 0; off >>= 1) {
        s += __shfl_down(s, off);
        sq += __shfl_down(sq, off);
    }
    __shared__ float red[8];
    int w = c >> 6;
    if ((c & 63) == 0) { red[w] = s; red[4 + w] = sq; }
    __syncthreads();
    s = red[0] + red[1] + red[2] + red[3];
    sq = red[4] + red[5] + red[6] + red[7];
    float mu = s * (1.f / 256.f);
    float var = sq * (1.f / 256.f) - mu * mu;
    float rs = rsqrtf(var + 1e-5f);
    float xn = (v - mu) * rs * g[c] + b[c];
    int np = (c >> 6) * 2 + n;
    parts[(((size_t)np * 4096 + l) * 64) + (c & 63)] = xn;
}

// ---------------- LayerNorm 2: row-major [8192][256] -> [8192][256] ---------
__global__ __launch_bounds__(256) void ln2_kernel(
    const float* __restrict__ xm, const float* __restrict__ g,
    const float* __restrict__ b, float* __restrict__ o) {
    int row = blockIdx.x;          // 8192
    int c = threadIdx.x;
    float v = xm[(size_t)row * 256 + c];
    float s = v, sq = v * v;
    #pragma unroll
    for (int off = 32; off > 0; off >>= 1) {
        s += __shfl_down(s, off);
        sq += __shfl_down(sq, off);
    }
    __shared__ float red[8];
    int w = c >> 6;
    if ((c & 63) == 0) { red[w] = s; red[4 + w] = sq; }
    __syncthreads();
    s = red[0] + red[1] + red[2] + red[3];
    sq = red[4] + red[5] + red[6] + red[7];
    float mu = s * (1.f / 256.f);
    float var = sq * (1.f / 256.f) - mu * mu;
    float rs = rsqrtf(var + 1e-5f);
    o[(size_t)row * 256 + c] = (v - mu) * rs * g[c] + b[c];
}

// ---------------- causal depthwise conv(4) + SiLU ---------------------------
// u0 = xz cols [0,128); u[row][d] = silu(conv_b[d] + sum_j w[d][j]*u0[l-3+j][d])
__global__ __launch_bounds__(256) void conv_silu_kernel(
    const float* __restrict__ xz, const float* __restrict__ cw,
    const float* __restrict__ cb, float* __restrict__ u) {
    int idx = blockIdx.x * 256 + threadIdx.x;   // 8*4096*128
    int d = idx & 127;
    int l = (idx >> 7) & 4095;
    int nn = idx >> 19;
    size_t base = ((size_t)nn * 4096) * 256 + d;
    float acc = cb[d];
    #pragma unroll
    for (int j = 0; j < 4; ++j) {
        int lj = l - 3 + j;
        if (lj >= 0) acc = fmaf(cw[d * 4 + j], xz[base + (size_t)lj * 256], acc);
    }
    float sig = 1.f / (1.f + __expf(-acc));
    u[idx] = acc * sig;
}

// ---------------- generic register-blocked fp32 GEMM ------------------------
// out[M][?] = A[M][K] * W[N][K]^T  (dot rows with rows), with epilogues:
// EPI 0: plain store, ld=N.
// EPI 1: store cols < N only, ld=N (N=36 padded tile).
// EPI 2: out_proj: += skip*parts[row][o]; scatter to x_mamba[n][l][p*64+o].
// EPI 3: final: += bias[o]; transposed store out[(n*256+o)*4096 + l].
template <int BM, int BN, int TM, int TN, int EPI>
__global__ __launch_bounds__(256) void gemm_k(
    const float* __restrict__ A, const float* __restrict__ W,
    float* __restrict__ out, int M, int N, int K,
    const float* __restrict__ e1, const float* __restrict__ e2) {
    constexpr int TX = BN / TN, TY = BM / TM;
    static_assert(TX * TY == 256, "bad tile");
    __shared__ float As[32][BM + 1];
    __shared__ float Ws[32][BN + 1];
    int tid = threadIdx.x;
    int tx = tid % TX, ty = tid / TX;
    int m0 = blockIdx.x * BM, n0 = blockIdx.y * BN;
    float acc[TM][TN] = {};
    for (int k0 = 0; k0 < K; k0 += 32) {
        for (int i = tid; i < BM * 8; i += 256) {
            int r = i >> 3, j = i & 7;
            const float4 v = *(const float4*)(A + (size_t)(m0 + r) * K + k0 + j * 4);
            As[j * 4 + 0][r] = v.x; As[j * 4 + 1][r] = v.y;
            As[j * 4 + 2][r] = v.z; As[j * 4 + 3][r] = v.w;
        }
        for (int i = tid; i < BN * 8; i += 256) {
            int r = i >> 3, j = i & 7;
            float4 v = make_float4(0.f, 0.f, 0.f, 0.f);
            if (EPI != 1 || (n0 + r) < N)
                v = *(const float4*)(W + (size_t)(n0 + r) * K + k0 + j * 4);
            Ws[j * 4 + 0][r] = v.x; Ws[j * 4 + 1][r] = v.y;
            Ws[j * 4 + 2][r] = v.z; Ws[j * 4 + 3][r] = v.w;
        }
        __syncthreads();
        #pragma unroll
        for (int k = 0; k < 32; ++k) {
            float af[TM], wf[TN];
            #pragma unroll
            for (int i = 0; i < TM; ++i) af[i] = As[k][ty * TM + i];
            #pragma unroll
            for (int j = 0; j < TN; ++j) wf[j] = Ws[k][tx * TN + j];
            #pragma unroll
            for (int i = 0; i < TM; ++i)
                #pragma unroll
                for (int j = 0; j < TN; ++j)
                    acc[i][j] = fmaf(af[i], wf[j], acc[i][j]);
        }
        __syncthreads();
    }
    if constexpr (EPI == 0) {
        #pragma unroll
        for (int i = 0; i < TM; ++i) {
            size_t row = m0 + ty * TM + i;
            float* op = out + row * (size_t)N + n0 + tx * TN;
            #pragma unroll
            for (int j = 0; j < TN; j += 4)
                *(float4*)(op + j) = make_float4(acc[i][j], acc[i][j + 1],
                                                 acc[i][j + 2], acc[i][j + 3]);
        }
    } else if constexpr (EPI == 1) {
        #pragma unroll
        for (int i = 0; i < TM; ++i) {
            size_t row = m0 + ty * TM + i;
            #pragma unroll
            for (int j = 0; j < TN; ++j) {
                int gn = n0 + tx * TN + j;
                if (gn < N) out[row * (size_t)N + gn] = acc[i][j];
            }
        }
    } else if constexpr (EPI == 2) {
        float skip = e2[0];
        #pragma unroll
        for (int i = 0; i < TM; ++i) {
            int row = m0 + ty * TM + i;
            int np = row >> 12, l = row & 4095;
            int n = np & 1, p = np >> 1;
            int o0 = n0 + tx * TN;   // TN == 4
            const float4 pv = *(const float4*)(e1 + (size_t)row * 64 + o0);
            float4 v = make_float4(fmaf(skip, pv.x, acc[i][0]),
                                   fmaf(skip, pv.y, acc[i][1]),
                                   fmaf(skip, pv.z, acc[i][2]),
                                   fmaf(skip, pv.w, acc[i][3]));
            *(float4*)(out + ((size_t)(n * 4096 + l)) * 256 + p * 64 + o0) = v;
        }
    } else {  // EPI == 3, TM == 4
        int row0 = m0 + ty * TM;
        int n = row0 >> 12, l = row0 & 4095;
        #pragma unroll
        for (int j = 0; j < TN; ++j) {
            int o = n0 + tx * TN + j;
            float bias = e1[o];
            float4 v = make_float4(acc[0][j] + bias, acc[1][j] + bias,
                                   acc[2][j] + bias, acc[3][j] + bias);
            *(float4*)(out + ((size_t)(n * 256 + o)) * 4096 + l) = v;
        }
    }
}

// ---------------- chunked selective scan ------------------------------------
// 32 chunks of 128 steps. Chains: (n,d,k), chain id = (n*16+k)*128 + d.
// Thread t of block (n,chunk): d = t&127, owns k = (t>>7)*8 .. +8.
__global__ __launch_bounds__(256) void scan_pass1(
    const float* __restrict__ dbc, const float* __restrict__ u,
    const float* __restrict__ dtw, const float* __restrict__ dtb,
    const float* __restrict__ Alog,
    float* __restrict__ P, float* __restrict__ S) {
    int blk = blockIdx.x;          // 8n * 32c
    int n = blk >> 5, c = blk & 31;
    int t = threadIdx.x, d = t & 127, kh = t >> 7;
    float a2[8];
    #pragma unroll
    for (int j = 0; j < 8; ++j)
        a2[j] = -__expf(Alog[d * 16 + kh * 8 + j]) * LOG2E;
    float w0 = dtw[d * 4 + 0], w1 = dtw[d * 4 + 1];
    float w2 = dtw[d * 4 + 2], w3 = dtw[d * 4 + 3];
    float bias = dtb[d];
    float h[8], ap[8];
    #pragma unroll
    for (int j = 0; j < 8; ++j) { h[j] = 0.f; ap[j] = 1.f; }
    int l0 = c * 128;
    const float* dbp = dbc + (size_t)(n * 4096 + l0) * 36;
    const float* up = u + (size_t)(n * 4096 + l0) * 128 + d;
    for (int s = 0; s < 128; ++s) {
        float dtraw = fmaf(w0, dbp[0], fmaf(w1, dbp[1],
                      fmaf(w2, dbp[2], fmaf(w3, dbp[3], bias))));
        float dt = softplusf(dtraw);
        float uv = *up;
        float dtu = dt * uv;
        const float* Bp = dbp + 4 + kh * 8;
        #pragma unroll
        for (int j = 0; j < 8; ++j) {
            float a = exp2f(dt * a2[j]);
            h[j] = fmaf(a, h[j], dtu * Bp[j]);
            ap[j] *= a;
        }
        dbp += 36; up += 128;
    }
    int chain0 = n * 2048 + kh * 1024 + d;
    #pragma unroll
    for (int j = 0; j < 8; ++j) {
        P[(size_t)c * 16384 + chain0 + j * 128] = ap[j];
        S[(size_t)c * 16384 + chain0 + j * 128] = h[j];
    }
}

__global__ __launch_bounds__(256) void scan_combine(
    const float* __restrict__ P, const float* __restrict__ S,
    float* __restrict__ H) {
    int chain = blockIdx.x * 256 + threadIdx.x;   // 16384
    float h = 0.f;
    for (int c = 0; c < 32; ++c) {
        H[(size_t)c * 16384 + chain] = h;
        h = fmaf(P[(size_t)c * 16384 + chain], h, S[(size_t)c * 16384 + chain]);
    }
}

__global__ __launch_bounds__(256) void scan_pass2(
    const float* __restrict__ dbc, const float* __restrict__ u,
    const float* __restrict__ xz,
    const float* __restrict__ dtw, const float* __restrict__ dtb,
    const float* __restrict__ Alog, const float* __restrict__ Dp,
    const float* __restrict__ H, float* __restrict__ y) {
    int blk = blockIdx.x;
    int n = blk >> 5, c = blk & 31;
    int t = threadIdx.x, d = t & 127, kh = t >> 7;
    float a2[8];
    #pragma unroll
    for (int j = 0; j < 8; ++j)
        a2[j] = -__expf(Alog[d * 16 + kh * 8 + j]) * LOG2E;
    float w0 = dtw[d * 4 + 0], w1 = dtw[d * 4 + 1];
    float w2 = dtw[d * 4 + 2], w3 = dtw[d * 4 + 3];
    float bias = dtb[d];
    int chain0 = n * 2048 + kh * 1024 + d;
    float h[8];
    #pragma unroll
    for (int j = 0; j < 8; ++j) h[j] = H[(size_t)c * 16384 + chain0 + j * 128];
    __shared__ float part[8][256];
    int l0 = c * 128;
    for (int tile = 0; tile < 16; ++tile) {
        for (int s = 0; s < 8; ++s) {
            int l = l0 + tile * 8 + s;
            const float* dbp = dbc + (size_t)(n * 4096 + l) * 36;
            float dtraw = fmaf(w0, dbp[0], fmaf(w1, dbp[1],
                          fmaf(w2, dbp[2], fmaf(w3, dbp[3], bias))));
            float dt = softplusf(dtraw);
            float uv = u[(size_t)(n * 4096 + l) * 128 + d];
            float dtu = dt * uv;
            const float* Bp = dbp + 4 + kh * 8;
            const float* Cp = dbp + 20 + kh * 8;
            float ps = 0.f;
            #pragma unroll
            for (int j = 0; j < 8; ++j) {
                float a = exp2f(dt * a2[j]);
                h[j] = fmaf(a, h[j], dtu * Bp[j]);
                ps = fmaf(h[j], Cp[j], ps);
            }
            part[s][t] = ps;
        }
        __syncthreads();
        #pragma unroll
        for (int it = 0; it < 4; ++it) {
            int s2 = it * 2 + kh;
            int l = l0 + tile * 8 + s2;
            size_t row = (size_t)n * 4096 + l;
            float yv = part[s2][d] + part[s2][128 + d];
            float uv = u[row * 128 + d];
            float zv = xz[row * 256 + 128 + d];
            float sig = 1.f / (1.f + __expf(-zv));
            yv = (yv + Dp[d] * uv) * (zv * sig);
            y[row * 128 + d] = yv;
        }
        __syncthreads();
    }
}

// ---------------------------------------------------------------------------
extern "C" void kernel_launch(void* const* d_in, const int* in_sizes, int n_in,
                              void* d_out, int out_size, void* d_ws, size_t ws_size,
                              hipStream_t stream) {
    const float* x      = (const float*)d_in[0];
    const float* ln_g   = (const float*)d_in[1];
    const float* ln_b   = (const float*)d_in[2];
    const float* skip   = (const float*)d_in[3];
    const float* w_in   = (const float*)d_in[4];   // [256][64]
    const float* cw     = (const float*)d_in[5];   // [128][4]
    const float* cb     = (const float*)d_in[6];   // [128]
    const float* w_xp   = (const float*)d_in[7];   // [36][128]
    const float* dtw    = (const float*)d_in[8];   // [128][4]
    const float* dtb    = (const float*)d_in[9];   // [128]
    const float* Alog   = (const float*)d_in[10];  // [128][16]
    const float* Dp     = (const float*)d_in[11];  // [128]
    const float* w_out  = (const float*)d_in[12];  // [64][128]
    const float* w_proj = (const float*)d_in[13];  // [256][256]
    const float* proj_b = (const float*)d_in[14];  // [256]
    float* out = (float*)d_out;

    float* ws    = (float*)d_ws;
    float* parts = ws;                  // [32768][64]   2,097,152
    float* xz    = parts + 2097152;     // [32768][256]  8,388,608
    float* u     = xz + 8388608;        // [32768][128]  4,194,304
    float* dbc   = u + 4194304;         // [32768][36]   1,179,648
    float* P     = dbc + 1179648;       // [32][16384]     524,288
    float* S     = P + 524288;          //                 524,288
    float* H     = S + 524288;          //                 524,288
    float* y     = H + 524288;          // [32768][128]  4,194,304
    float* xm    = xz;                  // alias: xz dead after pass2
    float* xmn   = y;                   // alias: y dead after out_proj gemm

    ln1_kernel<<<8192, 256, 0, stream>>>(x, ln_g, ln_b, parts);
    gemm_k<128, 128, 8, 8, 0><<<dim3(256, 2), 256, 0, stream>>>(
        parts, w_in, xz, 32768, 256, 64, nullptr, nullptr);
    conv_silu_kernel<<<16384, 256, 0, stream>>>(xz, cw, cb, u);
    gemm_k<128, 64, 8, 4, 1><<<dim3(256, 1), 256, 0, stream>>>(
        u, w_xp, dbc, 32768, 36, 128, nullptr, nullptr);
    scan_pass1<<<256, 256, 0, stream>>>(dbc, u, dtw, dtb, Alog, P, S);
    scan_combine<<<64, 256, 0, stream>>>(P, S, H);
    scan_pass2<<<256, 256, 0, stream>>>(dbc, u, xz, dtw, dtb, Alog, Dp, H, y);
    gemm_k<128, 64, 8, 4, 2><<<dim3(256, 1), 256, 0, stream>>>(
        y, w_out, xm, 32768, 64, 128, parts, skip);
    ln2_kernel<<<8192, 256, 0, stream>>>(xm, ln_g, ln_b, xmn);
    gemm_k<64, 128, 4, 8, 3><<<dim3(128, 2), 256, 0, stream>>>(
        xmn, w_proj, out, 8192, 256, 256, proj_b, nullptr);
}

// Round 2
// 299.527 us; speedup vs baseline: 1.5871x; 1.5871x over previous
//
#include <hip/hip_runtime.h>
#include <hip/hip_bf16.h>

// ---------------------------------------------------------------------------
// PetaloMixer: LN -> (x4 groups) mamba block -> residual -> LN -> proj
// B=2, C=256, L=4096, d_model=64, d_inner=128, d_state=16, d_conv=4,
// dt_rank=4. Mamba batches N=8, rows = N*L = 32768. All fp32.
// R1: scan occupancy 256->1024 blocks (128 chunks x 32 steps), LDS-staged
//     dbc tiles, hw exp2/log, silu(z) precomputed, ws aliasing onto dead xz.
// ---------------------------------------------------------------------------

#define LOG2E 1.4426950408889634f
constexpr int NC = 128;   // chunks per sequence
constexpr int CS = 32;    // steps per chunk  (NC*CS == 4096)

__device__ __forceinline__ float hexp2(float x) { return __builtin_amdgcn_exp2f(x); }
__device__ __forceinline__ float hexp(float x)  { return __builtin_amdgcn_exp2f(x * LOG2E); }
__device__ __forceinline__ float hlog(float x)  { return __builtin_amdgcn_logf(x) * (1.f / LOG2E); }

// ---------------- LayerNorm 1: x[(n,c),l] -> parts[np=(p*2+n)][l][c'] -------
__global__ __launch_bounds__(256) void ln1_kernel(
    const float* __restrict__ x, const float* __restrict__ g,
    const float* __restrict__ b, float* __restrict__ parts) {
    int bid = blockIdx.x;          // 8192 = 2n * 4096l
    int n = bid >> 12, l = bid & 4095;
    int c = threadIdx.x;           // 256
    float v = x[((size_t)(n * 256 + c)) * 4096 + l];
    float s = v, sq = v * v;
    #pragma unroll
    for (int off = 32; off > 0; off >>= 1) {
        s += __shfl_down(s, off);
        sq += __shfl_down(sq, off);
    }
    __shared__ float red[8];
    int w = c >> 6;
    if ((c & 63) == 0) { red[w] = s; red[4 + w] = sq; }
    __syncthreads();
    s = red[0] + red[1] + red[2] + red[3];
    sq = red[4] + red[5] + red[6] + red[7];
    float mu = s * (1.f / 256.f);
    float var = sq * (1.f / 256.f) - mu * mu;
    float rs = rsqrtf(var + 1e-5f);
    float xn = (v - mu) * rs * g[c] + b[c];
    int np = (c >> 6) * 2 + n;
    parts[(((size_t)np * 4096 + l) * 64) + (c & 63)] = xn;
}

// ---------------- LayerNorm 2: row-major [8192][256] ------------------------
__global__ __launch_bounds__(256) void ln2_kernel(
    const float* __restrict__ xm, const float* __restrict__ g,
    const float* __restrict__ b, float* __restrict__ o) {
    int row = blockIdx.x;
    int c = threadIdx.x;
    float v = xm[(size_t)row * 256 + c];
    float s = v, sq = v * v;
    #pragma unroll
    for (int off = 32; off > 0; off >>= 1) {
        s += __shfl_down(s, off);
        sq += __shfl_down(sq, off);
    }
    __shared__ float red[8];
    int w = c >> 6;
    if ((c & 63) == 0) { red[w] = s; red[4 + w] = sq; }
    __syncthreads();
    s = red[0] + red[1] + red[2] + red[3];
    sq = red[4] + red[5] + red[6] + red[7];
    float mu = s * (1.f / 256.f);
    float var = sq * (1.f / 256.f) - mu * mu;
    float rs = rsqrtf(var + 1e-5f);
    o[(size_t)row * 256 + c] = (v - mu) * rs * g[c] + b[c];
}

// ------- causal depthwise conv(4)+SiLU on u0, and gz = silu(z) --------------
__global__ __launch_bounds__(256) void conv_gate_kernel(
    const float* __restrict__ xz, const float* __restrict__ cw,
    const float* __restrict__ cb, float* __restrict__ u,
    float* __restrict__ gz) {
    int idx = blockIdx.x * 256 + threadIdx.x;   // 8*4096*128
    int d = idx & 127;
    int l = (idx >> 7) & 4095;
    int nn = idx >> 19;
    size_t base = ((size_t)nn * 4096) * 256 + d;
    float acc = cb[d];
    #pragma unroll
    for (int j = 0; j < 4; ++j) {
        int lj = l - 3 + j;
        if (lj >= 0) acc = fmaf(cw[d * 4 + j], xz[base + (size_t)lj * 256], acc);
    }
    u[idx] = acc / (1.f + hexp(-acc));
    float zv = xz[base + (size_t)l * 256 + 128];
    gz[idx] = zv / (1.f + hexp(-zv));
}

// ---------------- generic register-blocked fp32 GEMM ------------------------
// out[M][?] = A[M][K] * W[N][K]^T, epilogues:
// 0: plain store. 1: store cols<N (padded tile). 2: out_proj +skip, scatter.
// 3: final +bias, transposed store.
template <int BM, int BN, int TM, int TN, int EPI>
__global__ __launch_bounds__(256) void gemm_k(
    const float* __restrict__ A, const float* __restrict__ W,
    float* __restrict__ out, int M, int N, int K,
    const float* __restrict__ e1, const float* __restrict__ e2) {
    constexpr int TX = BN / TN, TY = BM / TM;
    static_assert(TX * TY == 256, "bad tile");
    __shared__ float As[32][BM + 1];
    __shared__ float Ws[32][BN + 1];
    int tid = threadIdx.x;
    int tx = tid % TX, ty = tid / TX;
    int m0 = blockIdx.x * BM, n0 = blockIdx.y * BN;
    float acc[TM][TN] = {};
    for (int k0 = 0; k0 < K; k0 += 32) {
        for (int i = tid; i < BM * 8; i += 256) {
            int r = i >> 3, j = i & 7;
            const float4 v = *(const float4*)(A + (size_t)(m0 + r) * K + k0 + j * 4);
            As[j * 4 + 0][r] = v.x; As[j * 4 + 1][r] = v.y;
            As[j * 4 + 2][r] = v.z; As[j * 4 + 3][r] = v.w;
        }
        for (int i = tid; i < BN * 8; i += 256) {
            int r = i >> 3, j = i & 7;
            float4 v = make_float4(0.f, 0.f, 0.f, 0.f);
            if (EPI != 1 || (n0 + r) < N)
                v = *(const float4*)(W + (size_t)(n0 + r) * K + k0 + j * 4);
            Ws[j * 4 + 0][r] = v.x; Ws[j * 4 + 1][r] = v.y;
            Ws[j * 4 + 2][r] = v.z; Ws[j * 4 + 3][r] = v.w;
        }
        __syncthreads();
        #pragma unroll
        for (int k = 0; k < 32; ++k) {
            float af[TM], wf[TN];
            #pragma unroll
            for (int i = 0; i < TM; ++i) af[i] = As[k][ty * TM + i];
            #pragma unroll
            for (int j = 0; j < TN; ++j) wf[j] = Ws[k][tx * TN + j];
            #pragma unroll
            for (int i = 0; i < TM; ++i)
                #pragma unroll
                for (int j = 0; j < TN; ++j)
                    acc[i][j] = fmaf(af[i], wf[j], acc[i][j]);
        }
        __syncthreads();
    }
    if constexpr (EPI == 0) {
        #pragma unroll
        for (int i = 0; i < TM; ++i) {
            size_t row = m0 + ty * TM + i;
            float* op = out + row * (size_t)N + n0 + tx * TN;
            #pragma unroll
            for (int j = 0; j < TN; j += 4)
                *(float4*)(op + j) = make_float4(acc[i][j], acc[i][j + 1],
                                                 acc[i][j + 2], acc[i][j + 3]);
        }
    } else if constexpr (EPI == 1) {
        #pragma unroll
        for (int i = 0; i < TM; ++i) {
            size_t row = m0 + ty * TM + i;
            #pragma unroll
            for (int j = 0; j < TN; ++j) {
                int gn = n0 + tx * TN + j;
                if (gn < N) out[row * (size_t)N + gn] = acc[i][j];
            }
        }
    } else if constexpr (EPI == 2) {
        float skip = e2[0];
        #pragma unroll
        for (int i = 0; i < TM; ++i) {
            int row = m0 + ty * TM + i;
            int np = row >> 12, l = row & 4095;
            int n = np & 1, p = np >> 1;
            int o0 = n0 + tx * TN;   // TN == 4
            const float4 pv = *(const float4*)(e1 + (size_t)row * 64 + o0);
            float4 v = make_float4(fmaf(skip, pv.x, acc[i][0]),
                                   fmaf(skip, pv.y, acc[i][1]),
                                   fmaf(skip, pv.z, acc[i][2]),
                                   fmaf(skip, pv.w, acc[i][3]));
            *(float4*)(out + ((size_t)(n * 4096 + l)) * 256 + p * 64 + o0) = v;
        }
    } else {  // EPI == 3, TM == 4
        int row0 = m0 + ty * TM;
        int n = row0 >> 12, l = row0 & 4095;
        #pragma unroll
        for (int j = 0; j < TN; ++j) {
            int o = n0 + tx * TN + j;
            float bias = e1[o];
            float4 v = make_float4(acc[0][j] + bias, acc[1][j] + bias,
                                   acc[2][j] + bias, acc[3][j] + bias);
            *(float4*)(out + ((size_t)(n * 256 + o)) * 4096 + l) = v;
        }
    }
}

// ---------------- chunked selective scan ------------------------------------
// NC chunks of CS steps. Chains: (n,d,k), chain id = n*2048 + kh*1024 + j*128 + d.
// Block (n,chunk); thread t: d = t&127, kh = t>>7 owns k = kh*8..kh*8+7.
__global__ __launch_bounds__(256) void scan_pass1(
    const float* __restrict__ dbc, const float* __restrict__ u,
    const float* __restrict__ dtw, const float* __restrict__ dtb,
    const float* __restrict__ Alog,
    float* __restrict__ P, float* __restrict__ S) {
    int blk = blockIdx.x;          // 8n * NC
    int n = blk >> 7, c = blk & (NC - 1);
    int t = threadIdx.x, d = t & 127, kh = t >> 7;
    __shared__ float sD[CS * 36];
    int l0 = c * CS;
    const float* dsrc = dbc + (size_t)(n * 4096 + l0) * 36;
    for (int i = t; i < CS * 36; i += 256) sD[i] = dsrc[i];
    float a2[8];
    #pragma unroll
    for (int j = 0; j < 8; ++j)
        a2[j] = -hexp(Alog[d * 16 + kh * 8 + j]) * LOG2E;
    float w0 = dtw[d * 4 + 0], w1 = dtw[d * 4 + 1];
    float w2 = dtw[d * 4 + 2], w3 = dtw[d * 4 + 3];
    float bias = dtb[d];
    __syncthreads();
    float h[8], ap[8];
    #pragma unroll
    for (int j = 0; j < 8; ++j) { h[j] = 0.f; ap[j] = 1.f; }
    const float* up = u + (size_t)(n * 4096 + l0) * 128 + d;
    for (int s = 0; s < CS; ++s) {
        const float* dr = sD + s * 36;
        float dtraw = fmaf(w0, dr[0], fmaf(w1, dr[1],
                      fmaf(w2, dr[2], fmaf(w3, dr[3], bias))));
        float dt = (dtraw > 20.f) ? dtraw : hlog(1.f + hexp(dtraw));
        float dtu = dt * up[(size_t)s * 128];
        const float* Bp = dr + 4 + kh * 8;
        #pragma unroll
        for (int j = 0; j < 8; ++j) {
            float a = hexp2(dt * a2[j]);
            h[j] = fmaf(a, h[j], dtu * Bp[j]);
            ap[j] *= a;
        }
    }
    int chain0 = n * 2048 + kh * 1024 + d;
    #pragma unroll
    for (int j = 0; j < 8; ++j) {
        P[(size_t)c * 16384 + chain0 + j * 128] = ap[j];
        S[(size_t)c * 16384 + chain0 + j * 128] = h[j];
    }
}

// Sequential carry across chunks; rewrites P in place with the incoming state
// H[c] (prefix before chunk c).
__global__ __launch_bounds__(256) void scan_combine(
    float* __restrict__ P, const float* __restrict__ S) {
    int chain = blockIdx.x * 256 + threadIdx.x;   // 16384
    float h = 0.f;
    for (int c = 0; c < NC; ++c) {
        size_t idx = (size_t)c * 16384 + chain;
        float p = P[idx], s = S[idx];
        P[idx] = h;
        h = fmaf(p, h, s);
    }
}

__global__ __launch_bounds__(256) void scan_pass2(
    const float* __restrict__ dbc, const float* __restrict__ u,
    const float* __restrict__ gz,
    const float* __restrict__ dtw, const float* __restrict__ dtb,
    const float* __restrict__ Alog, const float* __restrict__ Dp,
    const float* __restrict__ H, float* __restrict__ y) {
    int blk = blockIdx.x;
    int n = blk >> 7, c = blk & (NC - 1);
    int t = threadIdx.x, d = t & 127, kh = t >> 7;
    __shared__ float sD[CS * 36];
    __shared__ float part[CS][256];
    int l0 = c * CS;
    const float* dsrc = dbc + (size_t)(n * 4096 + l0) * 36;
    for (int i = t; i < CS * 36; i += 256) sD[i] = dsrc[i];
    float a2[8];
    #pragma unroll
    for (int j = 0; j < 8; ++j)
        a2[j] = -hexp(Alog[d * 16 + kh * 8 + j]) * LOG2E;
    float w0 = dtw[d * 4 + 0], w1 = dtw[d * 4 + 1];
    float w2 = dtw[d * 4 + 2], w3 = dtw[d * 4 + 3];
    float bias = dtb[d];
    int chain0 = n * 2048 + kh * 1024 + d;
    float h[8];
    #pragma unroll
    for (int j = 0; j < 8; ++j) h[j] = H[(size_t)c * 16384 + chain0 + j * 128];
    __syncthreads();
    const float* up = u + (size_t)(n * 4096 + l0) * 128 + d;
    for (int s = 0; s < CS; ++s) {
        const float* dr = sD + s * 36;
        float dtraw = fmaf(w0, dr[0], fmaf(w1, dr[1],
                      fmaf(w2, dr[2], fmaf(w3, dr[3], bias))));
        float dt = (dtraw > 20.f) ? dtraw : hlog(1.f + hexp(dtraw));
        float dtu = dt * up[(size_t)s * 128];
        const float* Bp = dr + 4 + kh * 8;
        const float* Cp = dr + 20 + kh * 8;
        float ps = 0.f;
        #pragma unroll
        for (int j = 0; j < 8; ++j) {
            float a = hexp2(dt * a2[j]);
            h[j] = fmaf(a, h[j], dtu * Bp[j]);
            ps = fmaf(h[j], Cp[j], ps);
        }
        part[s][t] = ps;
    }
    __syncthreads();
    for (int i = t; i < CS * 128; i += 256) {
        int s = i >> 7, dd = i & 127;
        size_t row = (size_t)n * 4096 + l0 + s;
        float yv = part[s][dd] + part[s][128 + dd];
        yv = fmaf(Dp[dd], u[row * 128 + dd], yv) * gz[row * 128 + dd];
        y[row * 128 + dd] = yv;
    }
}

// ---------------------------------------------------------------------------
extern "C" void kernel_launch(void* const* d_in, const int* in_sizes, int n_in,
                              void* d_out, int out_size, void* d_ws, size_t ws_size,
                              hipStream_t stream) {
    const float* x      = (const float*)d_in[0];
    const float* ln_g   = (const float*)d_in[1];
    const float* ln_b   = (const float*)d_in[2];
    const float* skip   = (const float*)d_in[3];
    const float* w_in   = (const float*)d_in[4];   // [256][64]
    const float* cw     = (const float*)d_in[5];   // [128][4]
    const float* cb     = (const float*)d_in[6];   // [128]
    const float* w_xp   = (const float*)d_in[7];   // [36][128]
    const float* dtw    = (const float*)d_in[8];   // [128][4]
    const float* dtb    = (const float*)d_in[9];   // [128]
    const float* Alog   = (const float*)d_in[10];  // [128][16]
    const float* Dp     = (const float*)d_in[11];  // [128]
    const float* w_out  = (const float*)d_in[12];  // [64][128]
    const float* w_proj = (const float*)d_in[13];  // [256][256]
    const float* proj_b = (const float*)d_in[14];  // [256]
    float* out = (float*)d_out;

    float* ws    = (float*)d_ws;
    float* parts = ws;                  // [32768][64]   2,097,152
    float* xz    = parts + 2097152;     // [32768][256]  8,388,608 (dead after conv)
    float* u     = xz + 8388608;        // [32768][128]  4,194,304
    float* dbc   = u + 4194304;         // [32768][36]   1,179,648
    float* gz    = dbc + 1179648;       // [32768][128]  4,194,304
    // aliases into the dead xz region:
    float* P     = xz;                  // [NC][16384]   2,097,152 (becomes H)
    float* S     = xz + 2097152;        // [NC][16384]   2,097,152 (dead after combine)
    float* y     = xz + 4194304;        // [32768][128]  4,194,304
    float* xm    = xz + 2097152;        // [2][4096][256] 2,097,152 (over dead S)
    float* xmn   = xz + 4194304;        // [2][4096][256] 2,097,152 (over dead y)

    ln1_kernel<<<8192, 256, 0, stream>>>(x, ln_g, ln_b, parts);
    gemm_k<128, 128, 8, 8, 0><<<dim3(256, 2), 256, 0, stream>>>(
        parts, w_in, xz, 32768, 256, 64, nullptr, nullptr);
    conv_gate_kernel<<<16384, 256, 0, stream>>>(xz, cw, cb, u, gz);
    gemm_k<128, 64, 8, 4, 1><<<dim3(256, 1), 256, 0, stream>>>(
        u, w_xp, dbc, 32768, 36, 128, nullptr, nullptr);
    scan_pass1<<<8 * NC, 256, 0, stream>>>(dbc, u, dtw, dtb, Alog, P, S);
    scan_combine<<<64, 256, 0, stream>>>(P, S);
    scan_pass2<<<8 * NC, 256, 0, stream>>>(dbc, u, gz, dtw, dtb, Alog, Dp, P, y);
    gemm_k<128, 64, 8, 4, 2><<<dim3(256, 1), 256, 0, stream>>>(
        y, w_out, xm, 32768, 64, 128, parts, skip);
    ln2_kernel<<<8192, 256, 0, stream>>>(xm, ln_g, ln_b, xmn);
    gemm_k<64, 128, 4, 8, 3><<<dim3(128, 2), 256, 0, stream>>>(
        xmn, w_proj, out, 8192, 256, 256, proj_b, nullptr);
}

// Round 3
// 232.371 us; speedup vs baseline: 2.0457x; 1.2890x over previous
//
#include <hip/hip_runtime.h>
#include <hip/hip_bf16.h>

// ---------------------------------------------------------------------------
// PetaloMixer: LN -> (x4 groups) mamba block -> residual -> LN -> proj
// B=2, C=256, L=4096, d_model=64, d_inner=128, d_state=16, d_conv=4,
// dt_rank=4. Mamba batches N=8, rows = N*L = 32768. All fp32.
// R2: x_proj fused into conv kernel; GEMMs re-tiled for occupancy
//     (1024-2048 blocks) with 16B-aligned padded LDS (stride+4) -> b128,
//     conflict-free inner reads; ln1 transposed through LDS (coalesced).
// ---------------------------------------------------------------------------

#define LOG2E 1.4426950408889634f
constexpr int NC = 128;   // scan chunks per sequence
constexpr int CS = 32;    // steps per chunk  (NC*CS == 4096)

__device__ __forceinline__ float hexp2(float x) { return __builtin_amdgcn_exp2f(x); }
__device__ __forceinline__ float hexp(float x)  { return __builtin_amdgcn_exp2f(x * LOG2E); }
__device__ __forceinline__ float hlog(float x)  { return __builtin_amdgcn_logf(x) * (1.f / LOG2E); }

// ---------------- LayerNorm 1 (transposed, coalesced) -----------------------
// x[(n,c),l] -> parts[np=(p*2+n)][l][c']  ; block = (n, 16-l chunk)
__global__ __launch_bounds__(256) void ln1_kernel(
    const float* __restrict__ x, const float* __restrict__ g,
    const float* __restrict__ b, float* __restrict__ parts) {
    int bid = blockIdx.x;            // 512 = 2n x 256 lchunks
    int n = bid >> 8, lc = bid & 255;
    int l0 = lc * 16;
    int t = threadIdx.x;
    __shared__ float T[256][17];
    __shared__ float redS[16][17];
    __shared__ float redQ[16][17];
    __shared__ float mu_s[16], rs_s[16];
    #pragma unroll
    for (int it = 0; it < 16; ++it) {
        int i = t + 256 * it;
        int c = i >> 4, l = i & 15;
        T[c][l] = x[(size_t)(n * 256 + c) * 4096 + l0 + l];
    }
    __syncthreads();
    {
        int l = t & 15, cg = t >> 4;
        float s = 0.f, sq = 0.f;
        #pragma unroll
        for (int j = 0; j < 16; ++j) {
            float v = T[cg * 16 + j][l];
            s += v; sq += v * v;
        }
        redS[l][cg] = s; redQ[l][cg] = sq;
    }
    __syncthreads();
    if (t < 16) {
        float ss = 0.f, qq = 0.f;
        #pragma unroll
        for (int j = 0; j < 16; ++j) { ss += redS[t][j]; qq += redQ[t][j]; }
        float mu = ss * (1.f / 256.f);
        float var = qq * (1.f / 256.f) - mu * mu;
        mu_s[t] = mu; rs_s[t] = rsqrtf(var + 1e-5f);
    }
    __syncthreads();
    #pragma unroll
    for (int it = 0; it < 16; ++it) {
        int i = t + 256 * it;
        int cp = i & 63;
        int pl = i >> 6;            // 0..63
        int p = pl >> 4, ll = pl & 15;
        int c = p * 64 + cp;
        float v = T[c][ll];
        float xn = (v - mu_s[ll]) * rs_s[ll] * g[c] + b[c];
        parts[((size_t)(p * 2 + n) * 4096 + l0 + ll) * 64 + cp] = xn;
    }
}

// ---------------- LayerNorm 2: row-major [8192][256] ------------------------
__global__ __launch_bounds__(256) void ln2_kernel(
    const float* __restrict__ xm, const float* __restrict__ g,
    const float* __restrict__ b, float* __restrict__ o) {
    int row = blockIdx.x;
    int c = threadIdx.x;
    float v = xm[(size_t)row * 256 + c];
    float s = v, sq = v * v;
    #pragma unroll
    for (int off = 32; off > 0; off >>= 1) {
        s += __shfl_down(s, off);
        sq += __shfl_down(sq, off);
    }
    __shared__ float red[8];
    int w = c >> 6;
    if ((c & 63) == 0) { red[w] = s; red[4 + w] = sq; }
    __syncthreads();
    s = red[0] + red[1] + red[2] + red[3];
    sq = red[4] + red[5] + red[6] + red[7];
    float mu = s * (1.f / 256.f);
    float var = sq * (1.f / 256.f) - mu * mu;
    float rs = rsqrtf(var + 1e-5f);
    o[(size_t)row * 256 + c] = (v - mu) * rs * g[c] + b[c];
}

// ------- fused: depthwise conv(4)+SiLU -> u, gz = silu(z), dbc = u*Wxp^T ----
// Block = (n, 32-row chunk). 1024 blocks.
__global__ __launch_bounds__(256) void conv_xproj_kernel(
    const float* __restrict__ xz, const float* __restrict__ cw,
    const float* __restrict__ cb, const float* __restrict__ wxp,
    float* __restrict__ u, float* __restrict__ gz, float* __restrict__ dbc) {
    int blk = blockIdx.x;
    int n = blk >> 7, c = blk & 127;
    int l0 = c * 32;
    int t = threadIdx.x, d = t & 127, rh = t >> 7;
    __shared__ float sU[32][132];
    __shared__ float sW[36][132];
    for (int i = t; i < 36 * 32; i += 256) {
        int nn = i >> 5, kc = i & 31;
        *(float4*)&sW[nn][kc * 4] = *(const float4*)(wxp + nn * 128 + kc * 4);
    }
    float cw0 = cw[d * 4], cw1 = cw[d * 4 + 1];
    float cw2 = cw[d * 4 + 2], cw3 = cw[d * 4 + 3];
    float cbd = cb[d];
    #pragma unroll 4
    for (int i = 0; i < 16; ++i) {
        int r = rh + 2 * i;
        int lg = l0 + r;
        size_t grow = (size_t)n * 4096 + lg;
        const float* xp = xz + grow * 256 + d;
        float acc = cbd;
        if (lg >= 3) {
            acc = fmaf(cw0, xp[-768], acc);
            acc = fmaf(cw1, xp[-512], acc);
            acc = fmaf(cw2, xp[-256], acc);
            acc = fmaf(cw3, xp[0], acc);
        } else {
            if (lg >= 3) acc = fmaf(cw0, xp[-768], acc);
            if (lg >= 2) acc = fmaf(cw1, xp[-512], acc);
            if (lg >= 1) acc = fmaf(cw2, xp[-256], acc);
            acc = fmaf(cw3, xp[0], acc);
        }
        float uv = acc / (1.f + hexp(-acc));
        sU[r][d] = uv;
        u[grow * 128 + d] = uv;
        float zv = xp[128];
        gz[grow * 128 + d] = zv / (1.f + hexp(-zv));
    }
    __syncthreads();
    // dbc: 16 r0 x 36 n pairs; each thread does rows r0 and r0+16
    for (int idx = t; idx < 16 * 36; idx += 256) {
        unsigned r0 = (unsigned)idx / 36u;
        unsigned nn = (unsigned)idx - r0 * 36u;
        float s0 = 0.f, s1 = 0.f;
        #pragma unroll
        for (int k4 = 0; k4 < 32; ++k4) {
            float4 wv = *(const float4*)&sW[nn][k4 * 4];
            float4 u0 = *(const float4*)&sU[r0][k4 * 4];
            float4 u1 = *(const float4*)&sU[r0 + 16][k4 * 4];
            s0 = fmaf(wv.x, u0.x, fmaf(wv.y, u0.y, fmaf(wv.z, u0.z, fmaf(wv.w, u0.w, s0))));
            s1 = fmaf(wv.x, u1.x, fmaf(wv.y, u1.y, fmaf(wv.z, u1.z, fmaf(wv.w, u1.w, s1))));
        }
        dbc[((size_t)n * 4096 + l0 + r0) * 36 + nn] = s0;
        dbc[((size_t)n * 4096 + l0 + r0 + 16) * 36 + nn] = s1;
    }
}

// ---------------- register-blocked fp32 GEMM --------------------------------
// out[M][N] = A[M][K] * W[N][K]^T, KC-chunked K staging, [K][BM+4] LDS
// (16B-aligned rows, odd bank stride). Epilogues:
// 0: plain store. 2: out_proj +skip, scatter. 3: final +bias, transposed.
template <int BM, int BN, int TM, int TN, int KC, int EPI>
__global__ __launch_bounds__(256) void gemm_k(
    const float* __restrict__ A, const float* __restrict__ W,
    float* __restrict__ out, int M, int N, int K,
    const float* __restrict__ e1, const float* __restrict__ e2) {
    constexpr int TX = BN / TN, TY = BM / TM;
    static_assert(TX * TY == 256, "bad tile");
    __shared__ float As[KC][BM + 4];
    __shared__ float Ws[KC][BN + 4];
    int tid = threadIdx.x;
    int tx = tid % TX, ty = tid / TX;
    int m0 = blockIdx.x * BM, n0 = blockIdx.y * BN;
    float acc[TM][TN] = {};
    for (int k0 = 0; k0 < K; k0 += KC) {
        for (int i = tid; i < BM * (KC / 4); i += 256) {
            int r = i / (KC / 4), kc = i % (KC / 4);
            const float4 v = *(const float4*)(A + (size_t)(m0 + r) * K + k0 + kc * 4);
            As[kc * 4 + 0][r] = v.x; As[kc * 4 + 1][r] = v.y;
            As[kc * 4 + 2][r] = v.z; As[kc * 4 + 3][r] = v.w;
        }
        for (int i = tid; i < BN * (KC / 4); i += 256) {
            int r = i / (KC / 4), kc = i % (KC / 4);
            const float4 v = *(const float4*)(W + (size_t)(n0 + r) * K + k0 + kc * 4);
            Ws[kc * 4 + 0][r] = v.x; Ws[kc * 4 + 1][r] = v.y;
            Ws[kc * 4 + 2][r] = v.z; Ws[kc * 4 + 3][r] = v.w;
        }
        __syncthreads();
        #pragma unroll
        for (int k = 0; k < KC; ++k) {
            float af[TM], wf[TN];
            #pragma unroll
            for (int i = 0; i < TM; ++i) af[i] = As[k][ty * TM + i];
            #pragma unroll
            for (int j = 0; j < TN; ++j) wf[j] = Ws[k][tx * TN + j];
            #pragma unroll
            for (int i = 0; i < TM; ++i)
                #pragma unroll
                for (int j = 0; j < TN; ++j)
                    acc[i][j] = fmaf(af[i], wf[j], acc[i][j]);
        }
        __syncthreads();
    }
    if constexpr (EPI == 0) {
        #pragma unroll
        for (int i = 0; i < TM; ++i) {
            size_t row = m0 + ty * TM + i;
            float* op = out + row * (size_t)N + n0 + tx * TN;
            #pragma unroll
            for (int j = 0; j < TN; j += 4)
                *(float4*)(op + j) = make_float4(acc[i][j], acc[i][j + 1],
                                                 acc[i][j + 2], acc[i][j + 3]);
        }
    } else if constexpr (EPI == 2) {
        float skip = e2[0];
        #pragma unroll
        for (int i = 0; i < TM; ++i) {
            int row = m0 + ty * TM + i;
            int np = row >> 12, l = row & 4095;
            int n = np & 1, p = np >> 1;
            int o0 = n0 + tx * TN;   // TN == 4
            const float4 pv = *(const float4*)(e1 + (size_t)row * 64 + o0);
            float4 v = make_float4(fmaf(skip, pv.x, acc[i][0]),
                                   fmaf(skip, pv.y, acc[i][1]),
                                   fmaf(skip, pv.z, acc[i][2]),
                                   fmaf(skip, pv.w, acc[i][3]));
            *(float4*)(out + ((size_t)(n * 4096 + l)) * 256 + p * 64 + o0) = v;
        }
    } else {  // EPI == 3, TM == 4
        int row0 = m0 + ty * TM;
        int n = row0 >> 12, l = row0 & 4095;
        #pragma unroll
        for (int j = 0; j < TN; ++j) {
            int o = n0 + tx * TN + j;
            float bias = e1[o];
            float4 v = make_float4(acc[0][j] + bias, acc[1][j] + bias,
                                   acc[2][j] + bias, acc[3][j] + bias);
            *(float4*)(out + ((size_t)(n * 256 + o)) * 4096 + l) = v;
        }
    }
}

// ---------------- chunked selective scan ------------------------------------
__global__ __launch_bounds__(256) void scan_pass1(
    const float* __restrict__ dbc, const float* __restrict__ u,
    const float* __restrict__ dtw, const float* __restrict__ dtb,
    const float* __restrict__ Alog,
    float* __restrict__ P, float* __restrict__ S) {
    int blk = blockIdx.x;          // 8n * NC
    int n = blk >> 7, c = blk & (NC - 1);
    int t = threadIdx.x, d = t & 127, kh = t >> 7;
    __shared__ float sD[CS * 36];
    int l0 = c * CS;
    const float* dsrc = dbc + (size_t)(n * 4096 + l0) * 36;
    for (int i = t; i < CS * 36; i += 256) sD[i] = dsrc[i];
    float a2[8];
    #pragma unroll
    for (int j = 0; j < 8; ++j)
        a2[j] = -hexp(Alog[d * 16 + kh * 8 + j]) * LOG2E;
    float w0 = dtw[d * 4 + 0], w1 = dtw[d * 4 + 1];
    float w2 = dtw[d * 4 + 2], w3 = dtw[d * 4 + 3];
    float bias = dtb[d];
    __syncthreads();
    float h[8], ap[8];
    #pragma unroll
    for (int j = 0; j < 8; ++j) { h[j] = 0.f; ap[j] = 1.f; }
    const float* up = u + (size_t)(n * 4096 + l0) * 128 + d;
    for (int s = 0; s < CS; ++s) {
        const float* dr = sD + s * 36;
        float dtraw = fmaf(w0, dr[0], fmaf(w1, dr[1],
                      fmaf(w2, dr[2], fmaf(w3, dr[3], bias))));
        float dt = (dtraw > 20.f) ? dtraw : hlog(1.f + hexp(dtraw));
        float dtu = dt * up[(size_t)s * 128];
        const float* Bp = dr + 4 + kh * 8;
        #pragma unroll
        for (int j = 0; j < 8; ++j) {
            float a = hexp2(dt * a2[j]);
            h[j] = fmaf(a, h[j], dtu * Bp[j]);
            ap[j] *= a;
        }
    }
    int chain0 = n * 2048 + kh * 1024 + d;
    #pragma unroll
    for (int j = 0; j < 8; ++j) {
        P[(size_t)c * 16384 + chain0 + j * 128] = ap[j];
        S[(size_t)c * 16384 + chain0 + j * 128] = h[j];
    }
}

// Sequential carry; rewrites P in place with prefix state before chunk c.
__global__ __launch_bounds__(256) void scan_combine(
    float* __restrict__ P, const float* __restrict__ S) {
    int chain = blockIdx.x * 256 + threadIdx.x;   // 16384
    float h = 0.f;
    for (int c = 0; c < NC; ++c) {
        size_t idx = (size_t)c * 16384 + chain;
        float p = P[idx], s = S[idx];
        P[idx] = h;
        h = fmaf(p, h, s);
    }
}

__global__ __launch_bounds__(256) void scan_pass2(
    const float* __restrict__ dbc, const float* __restrict__ u,
    const float* __restrict__ gz,
    const float* __restrict__ dtw, const float* __restrict__ dtb,
    const float* __restrict__ Alog, const float* __restrict__ Dp,
    const float* __restrict__ H, float* __restrict__ y) {
    int blk = blockIdx.x;
    int n = blk >> 7, c = blk & (NC - 1);
    int t = threadIdx.x, d = t & 127, kh = t >> 7;
    __shared__ float sD[CS * 36];
    __shared__ float part[CS][256];
    int l0 = c * CS;
    const float* dsrc = dbc + (size_t)(n * 4096 + l0) * 36;
    for (int i = t; i < CS * 36; i += 256) sD[i] = dsrc[i];
    float a2[8];
    #pragma unroll
    for (int j = 0; j < 8; ++j)
        a2[j] = -hexp(Alog[d * 16 + kh * 8 + j]) * LOG2E;
    float w0 = dtw[d * 4 + 0], w1 = dtw[d * 4 + 1];
    float w2 = dtw[d * 4 + 2], w3 = dtw[d * 4 + 3];
    float bias = dtb[d];
    int chain0 = n * 2048 + kh * 1024 + d;
    float h[8];
    #pragma unroll
    for (int j = 0; j < 8; ++j) h[j] = H[(size_t)c * 16384 + chain0 + j * 128];
    __syncthreads();
    const float* up = u + (size_t)(n * 4096 + l0) * 128 + d;
    for (int s = 0; s < CS; ++s) {
        const float* dr = sD + s * 36;
        float dtraw = fmaf(w0, dr[0], fmaf(w1, dr[1],
                      fmaf(w2, dr[2], fmaf(w3, dr[3], bias))));
        float dt = (dtraw > 20.f) ? dtraw : hlog(1.f + hexp(dtraw));
        float dtu = dt * up[(size_t)s * 128];
        const float* Bp = dr + 4 + kh * 8;
        const float* Cp = dr + 20 + kh * 8;
        float ps = 0.f;
        #pragma unroll
        for (int j = 0; j < 8; ++j) {
            float a = hexp2(dt * a2[j]);
            h[j] = fmaf(a, h[j], dtu * Bp[j]);
            ps = fmaf(h[j], Cp[j], ps);
        }
        part[s][t] = ps;
    }
    __syncthreads();
    for (int i = t; i < CS * 128; i += 256) {
        int s = i >> 7, dd = i & 127;
        size_t row = (size_t)n * 4096 + l0 + s;
        float yv = part[s][dd] + part[s][128 + dd];
        yv = fmaf(Dp[dd], u[row * 128 + dd], yv) * gz[row * 128 + dd];
        y[row * 128 + dd] = yv;
    }
}

// ---------------------------------------------------------------------------
extern "C" void kernel_launch(void* const* d_in, const int* in_sizes, int n_in,
                              void* d_out, int out_size, void* d_ws, size_t ws_size,
                              hipStream_t stream) {
    const float* x      = (const float*)d_in[0];
    const float* ln_g   = (const float*)d_in[1];
    const float* ln_b   = (const float*)d_in[2];
    const float* skip   = (const float*)d_in[3];
    const float* w_in   = (const float*)d_in[4];   // [256][64]
    const float* cw     = (const float*)d_in[5];   // [128][4]
    const float* cb     = (const float*)d_in[6];   // [128]
    const float* w_xp   = (const float*)d_in[7];   // [36][128]
    const float* dtw    = (const float*)d_in[8];   // [128][4]
    const float* dtb    = (const float*)d_in[9];   // [128]
    const float* Alog   = (const float*)d_in[10];  // [128][16]
    const float* Dp     = (const float*)d_in[11];  // [128]
    const float* w_out  = (const float*)d_in[12];  // [64][128]
    const float* w_proj = (const float*)d_in[13];  // [256][256]
    const float* proj_b = (const float*)d_in[14];  // [256]
    float* out = (float*)d_out;

    float* ws    = (float*)d_ws;
    float* parts = ws;                  // [32768][64]   2,097,152
    float* xz    = parts + 2097152;     // [32768][256]  8,388,608 (dead after conv)
    float* u     = xz + 8388608;        // [32768][128]  4,194,304
    float* dbc   = u + 4194304;         // [32768][36]   1,179,648
    float* gz    = dbc + 1179648;       // [32768][128]  4,194,304
    // aliases into the dead xz region:
    float* P     = xz;                  // [NC][16384]   2,097,152 (becomes H)
    float* S     = xz + 2097152;        // [NC][16384]   2,097,152 (dead after combine)
    float* y     = xz + 4194304;        // [32768][128]  4,194,304
    float* xm    = xz + 2097152;        // [2][4096][256] 2,097,152 (over dead S)
    float* xmn   = xz + 4194304;        // [2][4096][256] 2,097,152 (over dead y)

    ln1_kernel<<<512, 256, 0, stream>>>(x, ln_g, ln_b, parts);
    gemm_k<64, 64, 4, 4, 64, 0><<<dim3(512, 4), 256, 0, stream>>>(
        parts, w_in, xz, 32768, 256, 64, nullptr, nullptr);
    conv_xproj_kernel<<<1024, 256, 0, stream>>>(xz, cw, cb, w_xp, u, gz, dbc);
    scan_pass1<<<8 * NC, 256, 0, stream>>>(dbc, u, dtw, dtb, Alog, P, S);
    scan_combine<<<64, 256, 0, stream>>>(P, S);
    scan_pass2<<<8 * NC, 256, 0, stream>>>(dbc, u, gz, dtw, dtb, Alog, Dp, P, y);
    gemm_k<32, 64, 2, 4, 64, 2><<<dim3(1024, 1), 256, 0, stream>>>(
        y, w_out, xm, 32768, 64, 128, parts, skip);
    ln2_kernel<<<8192, 256, 0, stream>>>(xm, ln_g, ln_b, xmn);
    gemm_k<64, 64, 4, 4, 64, 3><<<dim3(128, 4), 256, 0, stream>>>(
        xmn, w_proj, out, 8192, 256, 256, proj_b, nullptr);
}